// Round 1
// baseline (925.579 us; speedup 1.0000x reference)
//
#include <hip/hip_runtime.h>
#include <hip/hip_bf16.h>

// Problem constants (fixed by reference: M=4096, K=4096, N=12288, group=128)
constexpr int Mdim = 4096;
constexpr int Kdim = 4096;
constexpr int Ndim = 12288;

constexpr int TILE_M = 128;
constexpr int TILE_N = 128;
constexpr int TILE_K = 64;
constexpr int NKT = Kdim / TILE_K;      // 64 K-steps
constexpr int GRID_M = Mdim / TILE_M;   // 32
constexpr int GRID_N = Ndim / TILE_N;   // 96
constexpr int NWG = GRID_M * GRID_N;    // 3072 (divisible by 8 -> bijective XCD swizzle)

typedef float  f32x4  __attribute__((ext_vector_type(4)));
typedef __bf16 bf16x4v __attribute__((ext_vector_type(4)));
typedef __bf16 bf16x8v __attribute__((ext_vector_type(8)));
typedef int    i32x4  __attribute__((ext_vector_type(4)));

// Byte-offset swizzle inside a [128 rows][128 bytes] LDS tile.
// slot = 16B unit along K; f = s ^ ((row ^ row>>2) & 7) spreads both the
// fragment reads (16 consecutive rows @ fixed slot) and the staging writes
// (stride-4 rows @ fixed 8B position) to <=2-way bank aliasing.
__device__ __forceinline__ int swz(int row, int kbyte) {
    int s = kbyte >> 4;
    int f = s ^ ((row ^ (row >> 2)) & 7);
    return (row << 7) + (f << 4) + (kbyte & 15);
}

__launch_bounds__(256, 2)
__global__ void machete_fused(const float* __restrict__ A,
                              const int* __restrict__ Bq,
                              const float* __restrict__ S,
                              float* __restrict__ C) {
    __shared__ unsigned char sA[TILE_M * TILE_K * 2];  // 16 KB bf16, [row][k]
    __shared__ unsigned char sB[TILE_N * TILE_K * 2];  // 16 KB bf16, [col][k] (transposed)

    const int tid = threadIdx.x;
    const int bid = blockIdx.x;

    // XCD-aware swizzle (bijective since NWG % 8 == 0)
    const int sid = (bid & 7) * (NWG / 8) + (bid >> 3);
    const int tm = sid / GRID_N;
    const int tn = sid % GRID_N;
    const int brow = tm * TILE_M;
    const int bcol = tn * TILE_N;

    // ---- staging thread maps ----
    // A: 128 rows x 16 float4-chunks; thread: chunk kb = tid&15, row = tid>>4 (+16*i, i=0..7)
    const int a_row0 = tid >> 4;
    const int a_kb   = tid & 15;
    // B: per 4x4 block (4 k-rows x 4 cols): kb = tid>>4 (0..15), nb = tid&15, cols 4*nb + 64*i
    const int b_kb = tid >> 4;
    const int b_nb = tid & 15;

    int aw[8];
#pragma unroll
    for (int i = 0; i < 8; ++i) aw[i] = swz(a_row0 + 16 * i, a_kb * 8);
    int bw[2][4];
#pragma unroll
    for (int i = 0; i < 2; ++i)
#pragma unroll
        for (int j = 0; j < 4; ++j) bw[i][j] = swz(4 * b_nb + 64 * i + j, b_kb * 8);

    // ---- fragment read maps ----
    const int lane = tid & 63;
    const int w  = tid >> 6;
    const int wr = w >> 1, wc = w & 1;   // 2x2 wave grid, each wave 64x64 out
    const int fr = lane & 15;            // row/col within fragment
    const int ks = lane >> 4;            // k-slot 0..3 (8 bf16 each)
    int ar[4][2], br[4][2];
#pragma unroll
    for (int m = 0; m < 4; ++m)
#pragma unroll
        for (int kk = 0; kk < 2; ++kk) {
            ar[m][kk] = swz(wr * 64 + m * 16 + fr, kk * 64 + ks * 16);
            br[m][kk] = swz(wc * 64 + m * 16 + fr, kk * 64 + ks * 16);
        }

    const float* Ap = A + (long)brow * Kdim;
    const int*   Bp = Bq + bcol;

    f32x4 aregs[8];
    i32x4 bregs[2][4];
    f32x4 sregs[2];

    // prologue: load K-tile 0 into registers
#pragma unroll
    for (int i = 0; i < 8; ++i)
        aregs[i] = *(const f32x4*)(Ap + (long)(a_row0 + 16 * i) * Kdim + a_kb * 4);
#pragma unroll
    for (int i = 0; i < 2; ++i) {
#pragma unroll
        for (int r = 0; r < 4; ++r)
            bregs[i][r] = *(const i32x4*)(Bp + (long)(b_kb * 4 + r) * Ndim + 4 * b_nb + 64 * i);
        sregs[i] = *(const f32x4*)(S + bcol + 4 * b_nb + 64 * i);   // group 0
    }

    f32x4 acc[4][4];
#pragma unroll
    for (int m = 0; m < 4; ++m)
#pragma unroll
        for (int n = 0; n < 4; ++n) acc[m][n] = (f32x4){0.f, 0.f, 0.f, 0.f};

    for (int kt = 0; kt < NKT; ++kt) {
        // ---- write staged registers -> LDS (convert/dequant here) ----
#pragma unroll
        for (int i = 0; i < 8; ++i) {
            f32x4 v = aregs[i];
            bf16x4v p;
            p[0] = (__bf16)v[0]; p[1] = (__bf16)v[1];
            p[2] = (__bf16)v[2]; p[3] = (__bf16)v[3];
            *(bf16x4v*)(sA + aw[i]) = p;
        }
#pragma unroll
        for (int i = 0; i < 2; ++i) {
            f32x4 sc = sregs[i];
#pragma unroll
            for (int j = 0; j < 4; ++j) {
                float scj = sc[j];
                float nm8 = -8.f * scj;
                bf16x4v p;
#pragma unroll
                for (int r = 0; r < 4; ++r) {
                    float v = (float)bregs[i][r][j] * scj + nm8;  // (q-8)*s
                    p[r] = (__bf16)v;
                }
                *(bf16x4v*)(sB + bw[i][j]) = p;   // sB[col][k0..k0+3]
            }
        }
        __syncthreads();

        // ---- prefetch next K-tile globals into registers (hides under MFMA) ----
        if (kt + 1 < NKT) {
            const float* Ap2 = Ap + (kt + 1) * TILE_K;
            const int*   Bp2 = Bp + (long)((kt + 1) * TILE_K) * Ndim;
            const float* Sp2 = S + (long)((kt + 1) >> 1) * Ndim + bcol;
#pragma unroll
            for (int i = 0; i < 8; ++i)
                aregs[i] = *(const f32x4*)(Ap2 + (long)(a_row0 + 16 * i) * Kdim + a_kb * 4);
#pragma unroll
            for (int i = 0; i < 2; ++i) {
#pragma unroll
                for (int r = 0; r < 4; ++r)
                    bregs[i][r] = *(const i32x4*)(Bp2 + (long)(b_kb * 4 + r) * Ndim + 4 * b_nb + 64 * i);
                sregs[i] = *(const f32x4*)(Sp2 + 4 * b_nb + 64 * i);
            }
        }

        // ---- compute: 2 k-halves x 4x4 fragments ----
#pragma unroll
        for (int kk = 0; kk < 2; ++kk) {
            bf16x8v af[4], bfv[4];
#pragma unroll
            for (int m = 0; m < 4; ++m) af[m] = *(const bf16x8v*)(sA + ar[m][kk]);
#pragma unroll
            for (int n = 0; n < 4; ++n) bfv[n] = *(const bf16x8v*)(sB + br[n][kk]);
#pragma unroll
            for (int m = 0; m < 4; ++m)
#pragma unroll
                for (int n = 0; n < 4; ++n)
                    acc[m][n] = __builtin_amdgcn_mfma_f32_16x16x32_bf16(af[m], bfv[n], acc[m][n], 0, 0, 0);
        }
        __syncthreads();
    }

    // ---- epilogue: C/D layout col = lane&15, row = (lane>>4)*4 + r ----
#pragma unroll
    for (int m = 0; m < 4; ++m) {
        int row = brow + wr * 64 + m * 16 + ks * 4;
#pragma unroll
        for (int n = 0; n < 4; ++n) {
            int col = bcol + wc * 64 + n * 16 + fr;
            f32x4 v = acc[m][n];
            float* cp = C + (long)row * Ndim + col;
#pragma unroll
            for (int r = 0; r < 4; ++r) cp[(long)r * Ndim] = v[r];
        }
    }
}

extern "C" void kernel_launch(void* const* d_in, const int* in_sizes, int n_in,
                              void* d_out, int out_size, void* d_ws, size_t ws_size,
                              hipStream_t stream) {
    const float* A  = (const float*)d_in[0];
    const int*   Bq = (const int*)d_in[1];
    const float* S  = (const float*)d_in[2];
    float* C = (float*)d_out;
    hipLaunchKernelGGL(machete_fused, dim3(NWG), dim3(256), 0, stream, A, Bq, S, C);
}

// Round 2
// 562.796 us; speedup vs baseline: 1.6446x; 1.6446x over previous
//
#include <hip/hip_runtime.h>
#include <hip/hip_bf16.h>
#include <stdint.h>

// Problem constants (fixed by reference: M=4096, K=4096, N=12288, group=128)
constexpr int Mdim = 4096;
constexpr int Kdim = 4096;
constexpr int Ndim = 12288;

constexpr int TILE_M = 128;
constexpr int TILE_N = 128;
constexpr int TILE_K = 64;
constexpr int NKT = Kdim / TILE_K;      // 64 K-steps
constexpr int GRID_M = Mdim / TILE_M;   // 32
constexpr int GRID_N = Ndim / TILE_N;   // 96
constexpr int NWG = GRID_M * GRID_N;    // 3072

typedef float  f32x4   __attribute__((ext_vector_type(4)));
typedef __bf16 bf16x4v __attribute__((ext_vector_type(4)));
typedef __bf16 bf16x8v __attribute__((ext_vector_type(8)));
typedef int    i32x4   __attribute__((ext_vector_type(4)));
typedef unsigned short ushort8 __attribute__((ext_vector_type(8)));

// ---------------------------------------------------------------------------
// global_load_lds helper: per-lane global src, wave-uniform LDS dest (+lane*16)
// ---------------------------------------------------------------------------
typedef __attribute__((address_space(3))) uint32_t       lds_u32;
typedef __attribute__((address_space(1))) const uint32_t glb_u32;

__device__ __forceinline__ void gload16(const void* g, void* l) {
    __builtin_amdgcn_global_load_lds((glb_u32*)(uintptr_t)g,
                                     (lds_u32*)(uint32_t)(uintptr_t)l, 16, 0, 0);
}

// ===========================================================================
// Pre-pass 1: A fp32 [M][K] -> bf16 [M][K] with per-row 16B-chunk XOR swizzle
// (chunk s within each 8-chunk (=K-tile of 64) group stored at s ^ (row&7))
// ===========================================================================
__launch_bounds__(256)
__global__ void cvtA(const float* __restrict__ A, unsigned short* __restrict__ Aw) {
    int t = blockIdx.x * 256 + threadIdx.x;  // one 16B bf16 chunk (8 elems) per thread
    int r = t >> 9;                          // 512 chunks per row
    int c = t & 511;
    const float* src = A + ((long)r << 12) + (c << 3);
    f32x4 v0 = *(const f32x4*)src;
    f32x4 v1 = *(const f32x4*)(src + 4);
    bf16x8v o;
#pragma unroll
    for (int j = 0; j < 4; ++j) { o[j] = (__bf16)v0[j]; o[4 + j] = (__bf16)v1[j]; }
    int cs = (c & ~7) | ((c ^ r) & 7);       // XOR-swizzle within 8-chunk group
    *(bf16x8v*)(Aw + ((long)r << 12) + (cs << 3)) = o;
}

// ===========================================================================
// Pre-pass 2: Bq int32 [K][N] + scales -> bf16 B^T [N][K], same baked swizzle
// per 64x64 tile: coalesced read, dequant, LDS transpose, coalesced write
// ===========================================================================
__launch_bounds__(256)
__global__ void deqB(const int* __restrict__ Bq, const float* __restrict__ S,
                     unsigned short* __restrict__ Bw) {
    __shared__ unsigned short lt[64][72];    // 72: rows 144B apart -> 16B-aligned chunks
    int kb = blockIdx.x & 63;                // K/64
    int nb = blockIdx.x >> 6;                // N/64
    int k0 = kb << 6, n0 = nb << 6;
    int tid = threadIdx.x;
    int g = k0 >> 7;                         // scale group (128 | 64 tiles)
    int nq = (tid & 15) << 2;
    f32x4 sc = *(const f32x4*)(S + (long)g * Ndim + n0 + nq);
#pragma unroll
    for (int p = 0; p < 4; ++p) {
        int kk = (p << 4) + (tid >> 4);
        i32x4 q = *(const i32x4*)(Bq + (long)(k0 + kk) * Ndim + n0 + nq);
#pragma unroll
        for (int j = 0; j < 4; ++j) {
            float v = ((float)q[j] - 8.f) * sc[j];
            lt[nq + j][kk] = __builtin_bit_cast(unsigned short, (__bf16)v);
        }
    }
    __syncthreads();
#pragma unroll
    for (int h = 0; h < 2; ++h) {
        int cidx = tid + (h << 8);           // 512 chunks: n 0..63 x slot 0..7
        int n = cidx >> 3, s = cidx & 7;
        int sp = s ^ (n & 7);                // baked swizzle keyed by output row (=n)
        ushort8 v = *(const ushort8*)&lt[n][s << 3];
        *(ushort8*)(Bw + (long)(n0 + n) * Kdim + k0 + (sp << 3)) = v;
    }
}

// ===========================================================================
// Main GEMM: bf16 [M][K] x bf16 B^T [N][K] -> fp32 [M][N]
// m97 structure: 128x128 tile, BK=64, global_load_lds(16B), 2-barrier K-loop
// ===========================================================================
__launch_bounds__(256, 3)
__global__ void gemm_bf16(const unsigned short* __restrict__ Aw,
                          const unsigned short* __restrict__ Bw,
                          float* __restrict__ C) {
    __shared__ unsigned char sA[TILE_M * TILE_K * 2];  // 16 KB
    __shared__ unsigned char sB[TILE_N * TILE_K * 2];  // 16 KB

    const int tid  = threadIdx.x;
    const int lane = tid & 63;
    const int w    = tid >> 6;

    // XCD-partitioned schedule: XCD x (=bid%8) owns tn in [12x, 12x+12),
    // tm-major within a tn-panel -> B panel L2-resident, fetched once from HBM.
    const int bid   = blockIdx.x;
    const int x     = bid & 7;
    const int local = bid >> 3;              // 0..383
    const int pn    = local >> 5;            // 0..11
    const int tm    = local & 31;
    const int tn    = x * 12 + pn;
    const int brow  = tm << 7;
    const int bcol  = tn << 7;

    // ---- staging map: wave w, instr i covers LDS chunks w*256 + i*64 + lane
    const unsigned char* ga[4];
    const unsigned char* gb[4];
#pragma unroll
    for (int i = 0; i < 4; ++i) {
        int c = (w << 8) + (i << 6) + lane;
        int r = c >> 3, s = c & 7;
        ga[i] = (const unsigned char*)Aw + (long)(brow + r) * (Kdim * 2) + (s << 4);
        gb[i] = (const unsigned char*)Bw + (long)(bcol + r) * (Kdim * 2) + (s << 4);
    }

    // ---- fragment read offsets (LDS holds swizzled data: logical slot q at q^(r&7))
    const int fr = lane & 15;
    const int ks = lane >> 4;
    const int wr = w >> 1, wc = w & 1;       // 2x2 wave grid, 64x64 out each
    int ra[4][2], rb[4][2];
#pragma unroll
    for (int m = 0; m < 4; ++m)
#pragma unroll
        for (int kk = 0; kk < 2; ++kk) {
            int r_a = wr * 64 + m * 16 + fr;
            int r_b = wc * 64 + m * 16 + fr;
            ra[m][kk] = (r_a << 7) + ((((kk << 2) + ks) ^ (r_a & 7)) << 4);
            rb[m][kk] = (r_b << 7) + ((((kk << 2) + ks) ^ (r_b & 7)) << 4);
        }

    f32x4 acc[4][4];
#pragma unroll
    for (int m = 0; m < 4; ++m)
#pragma unroll
        for (int n = 0; n < 4; ++n) acc[m][n] = (f32x4){0.f, 0.f, 0.f, 0.f};

    for (int kt = 0; kt < NKT; ++kt) {
        // ---- stage current K-tile via direct global->LDS DMA ----
#pragma unroll
        for (int i = 0; i < 4; ++i) {
            gload16(ga[i], sA + (((w << 2) + i) << 10));
            gload16(gb[i], sB + (((w << 2) + i) << 10));
            ga[i] += TILE_K * 2;             // advance 128B per K-step
            gb[i] += TILE_K * 2;
        }
        __syncthreads();                     // compiler drains vmcnt before barrier

        // ---- compute: 2 k-halves x 4x4 fragments ----
#pragma unroll
        for (int kk = 0; kk < 2; ++kk) {
            bf16x8v af[4], bf[4];
#pragma unroll
            for (int m = 0; m < 4; ++m) af[m] = *(const bf16x8v*)(sA + ra[m][kk]);
#pragma unroll
            for (int n = 0; n < 4; ++n) bf[n] = *(const bf16x8v*)(sB + rb[n][kk]);
#pragma unroll
            for (int m = 0; m < 4; ++m)
#pragma unroll
                for (int n = 0; n < 4; ++n)
                    acc[m][n] = __builtin_amdgcn_mfma_f32_16x16x32_bf16(af[m], bf[n], acc[m][n], 0, 0, 0);
        }
        __syncthreads();
    }

    // ---- epilogue: C/D layout col = lane&15, row = (lane>>4)*4 + r ----
#pragma unroll
    for (int m = 0; m < 4; ++m) {
        int row = brow + wr * 64 + m * 16 + ks * 4;
#pragma unroll
        for (int n = 0; n < 4; ++n) {
            int col = bcol + wc * 64 + n * 16 + fr;
            f32x4 v = acc[m][n];
            float* cp = C + (long)row * Ndim + col;
#pragma unroll
            for (int r = 0; r < 4; ++r) cp[(long)r * Ndim] = v[r];
        }
    }
}

// ===========================================================================
// Fallback: round-1 fused kernel (used only if ws is too small)
// ===========================================================================
__device__ __forceinline__ int swz_f(int row, int kbyte) {
    int s = kbyte >> 4;
    int f = s ^ ((row ^ (row >> 2)) & 7);
    return (row << 7) + (f << 4) + (kbyte & 15);
}

__launch_bounds__(256, 2)
__global__ void machete_fused(const float* __restrict__ A,
                              const int* __restrict__ Bq,
                              const float* __restrict__ S,
                              float* __restrict__ C) {
    __shared__ unsigned char sA[TILE_M * TILE_K * 2];
    __shared__ unsigned char sB[TILE_N * TILE_K * 2];

    const int tid = threadIdx.x;
    const int bid = blockIdx.x;
    const int sid = (bid & 7) * (NWG / 8) + (bid >> 3);
    const int tm = sid / GRID_N;
    const int tn = sid % GRID_N;
    const int brow = tm * TILE_M;
    const int bcol = tn * TILE_N;

    const int a_row0 = tid >> 4;
    const int a_kb   = tid & 15;
    const int b_kb = tid >> 4;
    const int b_nb = tid & 15;

    int aw[8];
#pragma unroll
    for (int i = 0; i < 8; ++i) aw[i] = swz_f(a_row0 + 16 * i, a_kb * 8);
    int bw[2][4];
#pragma unroll
    for (int i = 0; i < 2; ++i)
#pragma unroll
        for (int j = 0; j < 4; ++j) bw[i][j] = swz_f(4 * b_nb + 64 * i + j, b_kb * 8);

    const int lane = tid & 63;
    const int w  = tid >> 6;
    const int wr = w >> 1, wc = w & 1;
    const int fr = lane & 15;
    const int ks = lane >> 4;
    int ar[4][2], br[4][2];
#pragma unroll
    for (int m = 0; m < 4; ++m)
#pragma unroll
        for (int kk = 0; kk < 2; ++kk) {
            ar[m][kk] = swz_f(wr * 64 + m * 16 + fr, kk * 64 + ks * 16);
            br[m][kk] = swz_f(wc * 64 + m * 16 + fr, kk * 64 + ks * 16);
        }

    const float* Ap = A + (long)brow * Kdim;
    const int*   Bp = Bq + bcol;

    f32x4 aregs[8];
    i32x4 bregs[2][4];
    f32x4 sregs[2];

#pragma unroll
    for (int i = 0; i < 8; ++i)
        aregs[i] = *(const f32x4*)(Ap + (long)(a_row0 + 16 * i) * Kdim + a_kb * 4);
#pragma unroll
    for (int i = 0; i < 2; ++i) {
#pragma unroll
        for (int r = 0; r < 4; ++r)
            bregs[i][r] = *(const i32x4*)(Bp + (long)(b_kb * 4 + r) * Ndim + 4 * b_nb + 64 * i);
        sregs[i] = *(const f32x4*)(S + bcol + 4 * b_nb + 64 * i);
    }

    f32x4 acc[4][4];
#pragma unroll
    for (int m = 0; m < 4; ++m)
#pragma unroll
        for (int n = 0; n < 4; ++n) acc[m][n] = (f32x4){0.f, 0.f, 0.f, 0.f};

    for (int kt = 0; kt < NKT; ++kt) {
#pragma unroll
        for (int i = 0; i < 8; ++i) {
            f32x4 v = aregs[i];
            bf16x4v p;
            p[0] = (__bf16)v[0]; p[1] = (__bf16)v[1];
            p[2] = (__bf16)v[2]; p[3] = (__bf16)v[3];
            *(bf16x4v*)(sA + aw[i]) = p;
        }
#pragma unroll
        for (int i = 0; i < 2; ++i) {
            f32x4 sc = sregs[i];
#pragma unroll
            for (int j = 0; j < 4; ++j) {
                float scj = sc[j];
                float nm8 = -8.f * scj;
                bf16x4v p;
#pragma unroll
                for (int r = 0; r < 4; ++r) {
                    float v = (float)bregs[i][r][j] * scj + nm8;
                    p[r] = (__bf16)v;
                }
                *(bf16x4v*)(sB + bw[i][j]) = p;
            }
        }
        __syncthreads();

        if (kt + 1 < NKT) {
            const float* Ap2 = Ap + (kt + 1) * TILE_K;
            const int*   Bp2 = Bp + (long)((kt + 1) * TILE_K) * Ndim;
            const float* Sp2 = S + (long)((kt + 1) >> 1) * Ndim + bcol;
#pragma unroll
            for (int i = 0; i < 8; ++i)
                aregs[i] = *(const f32x4*)(Ap2 + (long)(a_row0 + 16 * i) * Kdim + a_kb * 4);
#pragma unroll
            for (int i = 0; i < 2; ++i) {
#pragma unroll
                for (int r = 0; r < 4; ++r)
                    bregs[i][r] = *(const i32x4*)(Bp2 + (long)(b_kb * 4 + r) * Ndim + 4 * b_nb + 64 * i);
                sregs[i] = *(const f32x4*)(Sp2 + 4 * b_nb + 64 * i);
            }
        }

#pragma unroll
        for (int kk = 0; kk < 2; ++kk) {
            bf16x8v af[4], bfv[4];
#pragma unroll
            for (int m = 0; m < 4; ++m) af[m] = *(const bf16x8v*)(sA + ar[m][kk]);
#pragma unroll
            for (int n = 0; n < 4; ++n) bfv[n] = *(const bf16x8v*)(sB + br[n][kk]);
#pragma unroll
            for (int m = 0; m < 4; ++m)
#pragma unroll
                for (int n = 0; n < 4; ++n)
                    acc[m][n] = __builtin_amdgcn_mfma_f32_16x16x32_bf16(af[m], bfv[n], acc[m][n], 0, 0, 0);
        }
        __syncthreads();
    }

#pragma unroll
    for (int m = 0; m < 4; ++m) {
        int row = brow + wr * 64 + m * 16 + ks * 4;
#pragma unroll
        for (int n = 0; n < 4; ++n) {
            int col = bcol + wc * 64 + n * 16 + fr;
            f32x4 v = acc[m][n];
            float* cp = C + (long)row * Ndim + col;
#pragma unroll
            for (int r = 0; r < 4; ++r) cp[(long)r * Ndim] = v[r];
        }
    }
}

extern "C" void kernel_launch(void* const* d_in, const int* in_sizes, int n_in,
                              void* d_out, int out_size, void* d_ws, size_t ws_size,
                              hipStream_t stream) {
    const float* A  = (const float*)d_in[0];
    const int*   Bq = (const int*)d_in[1];
    const float* S  = (const float*)d_in[2];
    float* C = (float*)d_out;

    const size_t a_elems = (size_t)Mdim * Kdim;            // 16.8M bf16 = 32 MiB
    const size_t b_elems = (size_t)Ndim * Kdim;            // 50.3M bf16 = 96 MiB
    const size_t need = (a_elems + b_elems) * sizeof(unsigned short);

    if (ws_size >= need) {
        unsigned short* Aw = (unsigned short*)d_ws;
        unsigned short* Bw = Aw + a_elems;
        hipLaunchKernelGGL(cvtA, dim3((Mdim * Kdim / 8) / 256), dim3(256), 0, stream, A, Aw);
        hipLaunchKernelGGL(deqB, dim3((Kdim / 64) * (Ndim / 64)), dim3(256), 0, stream, Bq, S, Bw);
        hipLaunchKernelGGL(gemm_bf16, dim3(NWG), dim3(256), 0, stream, Aw, Bw, C);
    } else {
        hipLaunchKernelGGL(machete_fused, dim3(NWG), dim3(256), 0, stream, A, Bq, S, C);
    }
}

// Round 3
// 468.955 us; speedup vs baseline: 1.9737x; 1.2001x over previous
//
#include <hip/hip_runtime.h>
#include <hip/hip_bf16.h>
#include <stdint.h>

// Problem constants (fixed by reference: M=4096, K=4096, N=12288, group=128)
constexpr int Mdim = 4096;
constexpr int Kdim = 4096;
constexpr int Ndim = 12288;

constexpr int NKT = Kdim / 64;          // 64 K-tiles of BK=64
// 256x256 main tile grid
constexpr int GM256 = Mdim / 256;       // 16
constexpr int GN256 = Ndim / 256;       // 48
constexpr int NWG256 = GM256 * GN256;   // 768 (divisible by 8)
// 128x128 fallback grid
constexpr int GRID_M = Mdim / 128;      // 32
constexpr int GRID_N = Ndim / 128;      // 96
constexpr int NWG = GRID_M * GRID_N;    // 3072

typedef float  f32x4   __attribute__((ext_vector_type(4)));
typedef __bf16 bf16x4v __attribute__((ext_vector_type(4)));
typedef __bf16 bf16x8v __attribute__((ext_vector_type(8)));
typedef int    i32x4   __attribute__((ext_vector_type(4)));
typedef unsigned short ushort8 __attribute__((ext_vector_type(8)));

// ---------------------------------------------------------------------------
// global_load_lds: per-lane global src, wave-uniform LDS dest (+lane*16)
// ---------------------------------------------------------------------------
typedef __attribute__((address_space(3))) uint32_t       lds_u32;
typedef __attribute__((address_space(1))) const uint32_t glb_u32;

__device__ __forceinline__ void gload16(const void* g, void* l) {
    __builtin_amdgcn_global_load_lds((glb_u32*)(uintptr_t)g,
                                     (lds_u32*)(uint32_t)(uintptr_t)l, 16, 0, 0);
}

// ===========================================================================
// Swizzle scheme (baked into the prepass global layout):
// within each row, k organized as [kt 0..63][kh 0..1][slot 0..3][elem 0..7];
// logical slot ks stored at position ks ^ ((row>>1)&3). GEMM stages each
// (kt,kh) half linearly into LDS [kh][256 rows][4 slots]; fragment reads
// apply the same XOR -> balanced banks (8 dword-accesses/bank per wave).
// ===========================================================================

// Pre-pass 1: A fp32 [M][K] -> bf16 [M][K] with baked swizzle
__launch_bounds__(256)
__global__ void cvtA(const float* __restrict__ A, unsigned short* __restrict__ Aw) {
    int t = blockIdx.x * 256 + threadIdx.x;  // one 16B bf16 chunk (8 elems)
    int r = t >> 9;                          // 512 chunks per row
    int c = t & 511;
    const float* src = A + ((long)r << 12) + (c << 3);
    f32x4 v0 = *(const f32x4*)src;
    f32x4 v1 = *(const f32x4*)(src + 4);
    bf16x8v o;
#pragma unroll
    for (int j = 0; j < 4; ++j) { o[j] = (__bf16)v0[j]; o[4 + j] = (__bf16)v1[j]; }
    int ks = c & 3;
    int cp = (c & ~3) | (ks ^ ((r >> 1) & 3));
    *(bf16x8v*)(Aw + ((long)r << 12) + (cp << 3)) = o;
}

// Pre-pass 2: Bq int32 [K][N] + scales -> bf16 B^T [N][K], baked swizzle
__launch_bounds__(256)
__global__ void deqB(const int* __restrict__ Bq, const float* __restrict__ S,
                     unsigned short* __restrict__ Bw) {
    __shared__ unsigned short lt[64][72];    // 144B row pitch -> 16B-aligned chunks
    int kb = blockIdx.x & 63;                // K/64
    int nb = blockIdx.x >> 6;                // N/64
    int k0 = kb << 6, n0 = nb << 6;
    int tid = threadIdx.x;
    int g = k0 >> 7;                         // scale group
    int nq = (tid & 15) << 2;
    f32x4 sc = *(const f32x4*)(S + (long)g * Ndim + n0 + nq);
#pragma unroll
    for (int p = 0; p < 4; ++p) {
        int kk = (p << 4) + (tid >> 4);
        i32x4 q = *(const i32x4*)(Bq + (long)(k0 + kk) * Ndim + n0 + nq);
#pragma unroll
        for (int j = 0; j < 4; ++j) {
            float v = ((float)q[j] - 8.f) * sc[j];
            lt[nq + j][kk] = __builtin_bit_cast(unsigned short, (__bf16)v);
        }
    }
    __syncthreads();
#pragma unroll
    for (int h = 0; h < 2; ++h) {
        int cidx = tid + (h << 8);           // 512 chunks: n 0..63 x (kh,ks)
        int n = cidx >> 3, sidx = cidx & 7;
        int kh = sidx >> 2, ks = sidx & 3;
        int ksp = ks ^ ((n >> 1) & 3);       // n0 % 64 == 0 -> key consistent
        ushort8 v = *(const ushort8*)&lt[n][sidx << 3];
        *(ushort8*)(Bw + (long)(n0 + n) * Kdim + k0 + kh * 32 + ksp * 8) = v;
    }
}

// ===========================================================================
// Main GEMM: 256x256 tile, BK=64, 8 waves (2Mx4N), 8-phase schedule,
// counted vmcnt(4) per K-tile, 128 KiB double-buffered LDS.
// LDS buffer b at b*65536: A [kh][256][4ch] in [0,32K), B in [32K,64K).
// ===========================================================================
__launch_bounds__(512, 2)
__global__ void gemm256(const unsigned short* __restrict__ Aw,
                        const unsigned short* __restrict__ Bw,
                        float* __restrict__ C) {
    extern __shared__ unsigned char ldsbuf[];

    const int tid  = threadIdx.x;
    const int lane = tid & 63;
    const int w    = tid >> 6;               // wave 0..7
    const int wr   = w >> 2, wc = w & 3;     // 2x4 wave grid; wave tile 128x64
    const int fr   = lane & 15;
    const int ks   = lane >> 4;

    // XCD partition: xcd owns 6 tn panels; tm-major within panel (B L2-resident)
    const int bid = blockIdx.x;
    const int xcd = bid & 7;
    const int loc = bid >> 3;                // 0..95
    const int pn  = loc >> 4;                // 0..5
    const int tm  = loc & 15;                // 0..15
    const int tn  = xcd * 6 + pn;
    const int brow = tm << 8, bcol = tn << 8;

    // staging source bases: thread handles chunks tid and tid+512 of each half
    // chunk c: row=c>>2, pos=c&3; src = row*8192 + kt*128 + kh*64 + pos*16
    const unsigned char* baseA = (const unsigned char*)Aw
        + (size_t)(brow + (tid >> 2)) * 8192 + (size_t)(tid & 3) * 16;
    const unsigned char* baseB = (const unsigned char*)Bw
        + (size_t)(bcol + (tid >> 2)) * 8192 + (size_t)(tid & 3) * 16;

    // fragment read offsets (region-local)
    int offA[8][2], offB[4][2];
#pragma unroll
    for (int am = 0; am < 8; ++am)
#pragma unroll
        for (int kh = 0; kh < 2; ++kh) {
            int rowL = wr * 128 + am * 16 + fr;
            offA[am][kh] = (kh << 14) + rowL * 64 + ((ks ^ ((rowL >> 1) & 3)) << 4);
        }
#pragma unroll
    for (int n = 0; n < 4; ++n)
#pragma unroll
        for (int kh = 0; kh < 2; ++kh) {
            int colL = wc * 64 + n * 16 + fr;
            offB[n][kh] = (kh << 14) + colL * 64 + ((ks ^ ((colL >> 1) & 3)) << 4);
        }

    auto stageA = [&](int tile, int kh) {
        if (tile < NKT) {
            const unsigned char* s = baseA + (size_t)tile * 128 + (kh << 6);
            unsigned char* d = ldsbuf + ((tile & 1) << 16) + (kh << 14) + (w << 10);
            gload16(s, d);
            gload16(s + 1048576, d + 8192);   // +128 rows * 8192B
        }
    };
    auto stageB = [&](int tile, int kh) {
        if (tile < NKT) {
            const unsigned char* s = baseB + (size_t)tile * 128 + (kh << 6);
            unsigned char* d = ldsbuf + ((tile & 1) << 16) + 32768 + (kh << 14) + (w << 10);
            gload16(s, d);
            gload16(s + 1048576, d + 8192);
        }
    };

    f32x4 acc[8][4];
#pragma unroll
    for (int m = 0; m < 8; ++m)
#pragma unroll
        for (int n = 0; n < 4; ++n) acc[m][n] = (f32x4){0.f, 0.f, 0.f, 0.f};

    // prologue: K0 all 4 halves + K1 kh0 halves; vmcnt(4) -> K0 landed
    stageA(0, 0); stageB(0, 0); stageA(0, 1); stageB(0, 1);
    stageA(1, 0); stageB(1, 0);
    asm volatile("s_waitcnt vmcnt(4)" ::: "memory");
    __builtin_amdgcn_s_barrier();

    for (int T = 0; T < NKT; ++T) {
        unsigned char* sAc = ldsbuf + ((T & 1) << 16);
        unsigned char* sBc = sAc + 32768;
        bf16x8v bA[4], aF[4];

        // ---- phase 0: quadrant (mh0, kh0); stage A_kh1(T+1) ----
#pragma unroll
        for (int n = 0; n < 4; ++n) bA[n] = *(const bf16x8v*)(sBc + offB[n][0]);
#pragma unroll
        for (int m = 0; m < 4; ++m) aF[m] = *(const bf16x8v*)(sAc + offA[m][0]);
        stageA(T + 1, 1);
        __builtin_amdgcn_s_barrier();
        __builtin_amdgcn_s_setprio(1);
#pragma unroll
        for (int m = 0; m < 4; ++m)
#pragma unroll
            for (int n = 0; n < 4; ++n)
                acc[m][n] = __builtin_amdgcn_mfma_f32_16x16x32_bf16(aF[m], bA[n], acc[m][n], 0, 0, 0);
        __builtin_amdgcn_s_setprio(0);
        __builtin_amdgcn_s_barrier();

        // ---- phase 1: quadrant (mh1, kh0); stage B_kh1(T+1) ----
#pragma unroll
        for (int m = 0; m < 4; ++m) aF[m] = *(const bf16x8v*)(sAc + offA[4 + m][0]);
        stageB(T + 1, 1);
        __builtin_amdgcn_s_barrier();
        __builtin_amdgcn_s_setprio(1);
#pragma unroll
        for (int m = 0; m < 4; ++m)
#pragma unroll
            for (int n = 0; n < 4; ++n)
                acc[4 + m][n] = __builtin_amdgcn_mfma_f32_16x16x32_bf16(aF[m], bA[n], acc[4 + m][n], 0, 0, 0);
        __builtin_amdgcn_s_setprio(0);
        __builtin_amdgcn_s_barrier();

        // ---- phase 2: quadrant (mh0, kh1); stage A_kh0(T+2) ----
#pragma unroll
        for (int n = 0; n < 4; ++n) bA[n] = *(const bf16x8v*)(sBc + offB[n][1]);
#pragma unroll
        for (int m = 0; m < 4; ++m) aF[m] = *(const bf16x8v*)(sAc + offA[m][1]);
        stageA(T + 2, 0);
        __builtin_amdgcn_s_barrier();
        __builtin_amdgcn_s_setprio(1);
#pragma unroll
        for (int m = 0; m < 4; ++m)
#pragma unroll
            for (int n = 0; n < 4; ++n)
                acc[m][n] = __builtin_amdgcn_mfma_f32_16x16x32_bf16(aF[m], bA[n], acc[m][n], 0, 0, 0);
        __builtin_amdgcn_s_setprio(0);
        __builtin_amdgcn_s_barrier();

        // ---- phase 3: quadrant (mh1, kh1); stage B_kh0(T+2); K-tile vmcnt ----
#pragma unroll
        for (int m = 0; m < 4; ++m) aF[m] = *(const bf16x8v*)(sAc + offA[4 + m][1]);
        stageB(T + 2, 0);
        __builtin_amdgcn_s_barrier();
        __builtin_amdgcn_s_setprio(1);
#pragma unroll
        for (int m = 0; m < 4; ++m)
#pragma unroll
            for (int n = 0; n < 4; ++n)
                acc[4 + m][n] = __builtin_amdgcn_mfma_f32_16x16x32_bf16(aF[m], bA[n], acc[4 + m][n], 0, 0, 0);
        __builtin_amdgcn_s_setprio(0);
        // counted drain: newest 4 loads (kh0 of T+2) stay in flight;
        // everything needed for T+1 is guaranteed landed. Tail drains fully.
        if (T < NKT - 2) asm volatile("s_waitcnt vmcnt(4)" ::: "memory");
        else             asm volatile("s_waitcnt vmcnt(0)" ::: "memory");
        __builtin_amdgcn_s_barrier();
    }

    // epilogue: C/D layout col = lane&15, row = (lane>>4)*4 + r
#pragma unroll
    for (int am = 0; am < 8; ++am) {
        int row = brow + wr * 128 + am * 16 + ks * 4;
#pragma unroll
        for (int n = 0; n < 4; ++n) {
            int col = bcol + wc * 64 + n * 16 + fr;
            f32x4 v = acc[am][n];
            float* cp = C + (long)row * Ndim + col;
#pragma unroll
            for (int r = 0; r < 4; ++r) cp[(long)r * Ndim] = v[r];
        }
    }
}

// ===========================================================================
// Secondary fallback: round-2 128x128 structure, adapted to the new swizzle
// (used only if hipFuncSetAttribute fails)
// ===========================================================================
__launch_bounds__(256, 3)
__global__ void gemm_bf16(const unsigned short* __restrict__ Aw,
                          const unsigned short* __restrict__ Bw,
                          float* __restrict__ C) {
    __shared__ unsigned char sA[128 * 64 * 2];
    __shared__ unsigned char sB[128 * 64 * 2];

    const int tid  = threadIdx.x;
    const int lane = tid & 63;
    const int w    = tid >> 6;

    const int bid   = blockIdx.x;
    const int x     = bid & 7;
    const int local = bid >> 3;
    const int pn    = local >> 5;
    const int tm    = local & 31;
    const int tn    = x * 12 + pn;
    const int brow  = tm << 7;
    const int bcol  = tn << 7;

    const unsigned char* ga[4];
    const unsigned char* gb[4];
#pragma unroll
    for (int i = 0; i < 4; ++i) {
        int c = (w << 8) + (i << 6) + lane;
        int r = c >> 3, s = c & 7;
        ga[i] = (const unsigned char*)Aw + (long)(brow + r) * 8192 + (s << 4);
        gb[i] = (const unsigned char*)Bw + (long)(bcol + r) * 8192 + (s << 4);
    }

    const int fr = lane & 15;
    const int ks = lane >> 4;
    const int wr = w >> 1, wc = w & 1;
    int ra[4][2], rb[4][2];
#pragma unroll
    for (int m = 0; m < 4; ++m)
#pragma unroll
        for (int kk = 0; kk < 2; ++kk) {
            int r_a = wr * 64 + m * 16 + fr;
            int r_b = wc * 64 + m * 16 + fr;
            // new layout within row: [kh][slot^((r>>1)&3)]
            ra[m][kk] = (r_a << 7) + (kk << 6) + ((ks ^ ((r_a >> 1) & 3)) << 4);
            rb[m][kk] = (r_b << 7) + (kk << 6) + ((ks ^ ((r_b >> 1) & 3)) << 4);
        }

    f32x4 acc[4][4];
#pragma unroll
    for (int m = 0; m < 4; ++m)
#pragma unroll
        for (int n = 0; n < 4; ++n) acc[m][n] = (f32x4){0.f, 0.f, 0.f, 0.f};

    for (int kt = 0; kt < NKT; ++kt) {
#pragma unroll
        for (int i = 0; i < 4; ++i) {
            gload16(ga[i], sA + (((w << 2) + i) << 10));
            gload16(gb[i], sB + (((w << 2) + i) << 10));
            ga[i] += 128;
            gb[i] += 128;
        }
        __syncthreads();

#pragma unroll
        for (int kk = 0; kk < 2; ++kk) {
            bf16x8v af[4], bf[4];
#pragma unroll
            for (int m = 0; m < 4; ++m) af[m] = *(const bf16x8v*)(sA + ra[m][kk]);
#pragma unroll
            for (int n = 0; n < 4; ++n) bf[n] = *(const bf16x8v*)(sB + rb[n][kk]);
#pragma unroll
            for (int m = 0; m < 4; ++m)
#pragma unroll
                for (int n = 0; n < 4; ++n)
                    acc[m][n] = __builtin_amdgcn_mfma_f32_16x16x32_bf16(af[m], bf[n], acc[m][n], 0, 0, 0);
        }
        __syncthreads();
    }

#pragma unroll
    for (int m = 0; m < 4; ++m) {
        int row = brow + wr * 64 + m * 16 + ks * 4;
#pragma unroll
        for (int n = 0; n < 4; ++n) {
            int col = bcol + wc * 64 + n * 16 + fr;
            f32x4 v = acc[m][n];
            float* cp = C + (long)row * Ndim + col;
#pragma unroll
            for (int r = 0; r < 4; ++r) cp[(long)r * Ndim] = v[r];
        }
    }
}

// ===========================================================================
// Last-resort fallback: fused single-pass (no workspace needed)
// ===========================================================================
__device__ __forceinline__ int swz_f(int row, int kbyte) {
    int s = kbyte >> 4;
    int f = s ^ ((row ^ (row >> 2)) & 7);
    return (row << 7) + (f << 4) + (kbyte & 15);
}

__launch_bounds__(256, 2)
__global__ void machete_fused(const float* __restrict__ A,
                              const int* __restrict__ Bq,
                              const float* __restrict__ S,
                              float* __restrict__ C) {
    __shared__ unsigned char sA[128 * 64 * 2];
    __shared__ unsigned char sB[128 * 64 * 2];

    const int tid = threadIdx.x;
    const int bid = blockIdx.x;
    const int sid = (bid & 7) * (NWG / 8) + (bid >> 3);
    const int tm = sid / GRID_N;
    const int tn = sid % GRID_N;
    const int brow = tm * 128;
    const int bcol = tn * 128;

    const int a_row0 = tid >> 4;
    const int a_kb   = tid & 15;
    const int b_kb = tid >> 4;
    const int b_nb = tid & 15;

    int aw[8];
#pragma unroll
    for (int i = 0; i < 8; ++i) aw[i] = swz_f(a_row0 + 16 * i, a_kb * 8);
    int bw[2][4];
#pragma unroll
    for (int i = 0; i < 2; ++i)
#pragma unroll
        for (int j = 0; j < 4; ++j) bw[i][j] = swz_f(4 * b_nb + 64 * i + j, b_kb * 8);

    const int lane = tid & 63;
    const int w  = tid >> 6;
    const int wr = w >> 1, wc = w & 1;
    const int fr = lane & 15;
    const int ks = lane >> 4;
    int ar[4][2], br[4][2];
#pragma unroll
    for (int m = 0; m < 4; ++m)
#pragma unroll
        for (int kk = 0; kk < 2; ++kk) {
            ar[m][kk] = swz_f(wr * 64 + m * 16 + fr, kk * 64 + ks * 16);
            br[m][kk] = swz_f(wc * 64 + m * 16 + fr, kk * 64 + ks * 16);
        }

    const float* Ap = A + (long)brow * Kdim;
    const int*   Bp = Bq + bcol;

    f32x4 aregs[8];
    i32x4 bregs[2][4];
    f32x4 sregs[2];

#pragma unroll
    for (int i = 0; i < 8; ++i)
        aregs[i] = *(const f32x4*)(Ap + (long)(a_row0 + 16 * i) * Kdim + a_kb * 4);
#pragma unroll
    for (int i = 0; i < 2; ++i) {
#pragma unroll
        for (int r = 0; r < 4; ++r)
            bregs[i][r] = *(const i32x4*)(Bp + (long)(b_kb * 4 + r) * Ndim + 4 * b_nb + 64 * i);
        sregs[i] = *(const f32x4*)(S + bcol + 4 * b_nb + 64 * i);
    }

    f32x4 acc[4][4];
#pragma unroll
    for (int m = 0; m < 4; ++m)
#pragma unroll
        for (int n = 0; n < 4; ++n) acc[m][n] = (f32x4){0.f, 0.f, 0.f, 0.f};

    for (int kt = 0; kt < NKT; ++kt) {
#pragma unroll
        for (int i = 0; i < 8; ++i) {
            f32x4 v = aregs[i];
            bf16x4v p;
            p[0] = (__bf16)v[0]; p[1] = (__bf16)v[1];
            p[2] = (__bf16)v[2]; p[3] = (__bf16)v[3];
            *(bf16x4v*)(sA + aw[i]) = p;
        }
#pragma unroll
        for (int i = 0; i < 2; ++i) {
            f32x4 sc = sregs[i];
#pragma unroll
            for (int j = 0; j < 4; ++j) {
                float scj = sc[j];
                float nm8 = -8.f * scj;
                bf16x4v p;
#pragma unroll
                for (int r = 0; r < 4; ++r) {
                    float v = (float)bregs[i][r][j] * scj + nm8;
                    p[r] = (__bf16)v;
                }
                *(bf16x4v*)(sB + bw[i][j]) = p;
            }
        }
        __syncthreads();

        if (kt + 1 < NKT) {
            const float* Ap2 = Ap + (kt + 1) * 64;
            const int*   Bp2 = Bq + bcol + (long)((kt + 1) * 64) * Ndim;
            const float* Sp2 = S + (long)((kt + 1) >> 1) * Ndim + bcol;
#pragma unroll
            for (int i = 0; i < 8; ++i)
                aregs[i] = *(const f32x4*)(Ap2 + (long)(a_row0 + 16 * i) * Kdim + a_kb * 4);
#pragma unroll
            for (int i = 0; i < 2; ++i) {
#pragma unroll
                for (int r = 0; r < 4; ++r)
                    bregs[i][r] = *(const i32x4*)(Bp2 + (long)(b_kb * 4 + r) * Ndim + 4 * b_nb + 64 * i);
                sregs[i] = *(const f32x4*)(Sp2 + 4 * b_nb + 64 * i);
            }
        }

#pragma unroll
        for (int kk = 0; kk < 2; ++kk) {
            bf16x8v af[4], bfv[4];
#pragma unroll
            for (int m = 0; m < 4; ++m) af[m] = *(const bf16x8v*)(sA + ar[m][kk]);
#pragma unroll
            for (int n = 0; n < 4; ++n) bfv[n] = *(const bf16x8v*)(sB + br[n][kk]);
#pragma unroll
            for (int m = 0; m < 4; ++m)
#pragma unroll
                for (int n = 0; n < 4; ++n)
                    acc[m][n] = __builtin_amdgcn_mfma_f32_16x16x32_bf16(af[m], bfv[n], acc[m][n], 0, 0, 0);
        }
        __syncthreads();
    }

#pragma unroll
    for (int m = 0; m < 4; ++m) {
        int row = brow + wr * 64 + m * 16 + ks * 4;
#pragma unroll
        for (int n = 0; n < 4; ++n) {
            int col = bcol + wc * 64 + n * 16 + fr;
            f32x4 v = acc[m][n];
            float* cp = C + (long)row * Ndim + col;
#pragma unroll
            for (int r = 0; r < 4; ++r) cp[(long)r * Ndim] = v[r];
        }
    }
}

extern "C" void kernel_launch(void* const* d_in, const int* in_sizes, int n_in,
                              void* d_out, int out_size, void* d_ws, size_t ws_size,
                              hipStream_t stream) {
    const float* A  = (const float*)d_in[0];
    const int*   Bq = (const int*)d_in[1];
    const float* S  = (const float*)d_in[2];
    float* C = (float*)d_out;

    const size_t a_elems = (size_t)Mdim * Kdim;
    const size_t b_elems = (size_t)Ndim * Kdim;
    const size_t need = (a_elems + b_elems) * sizeof(unsigned short);

    if (ws_size >= need) {
        unsigned short* Aw = (unsigned short*)d_ws;
        unsigned short* Bw = Aw + a_elems;
        hipLaunchKernelGGL(cvtA, dim3((Mdim * Kdim / 8) / 256), dim3(256), 0, stream, A, Aw);
        hipLaunchKernelGGL(deqB, dim3((Kdim / 64) * (Ndim / 64)), dim3(256), 0, stream, Bq, S, Bw);
        hipError_t e = hipFuncSetAttribute(
            reinterpret_cast<const void*>(gemm256),
            hipFuncAttributeMaxDynamicSharedMemorySize, 131072);
        if (e == hipSuccess) {
            hipLaunchKernelGGL(gemm256, dim3(NWG256), dim3(512), 131072, stream, Aw, Bw, C);
        } else {
            hipLaunchKernelGGL(gemm_bf16, dim3(NWG), dim3(256), 0, stream, Aw, Bw, C);
        }
    } else {
        hipLaunchKernelGGL(machete_fused, dim3(NWG), dim3(256), 0, stream, A, Bq, S, C);
    }
}

// Round 4
// 463.354 us; speedup vs baseline: 1.9976x; 1.0121x over previous
//
#include <hip/hip_runtime.h>
#include <hip/hip_bf16.h>
#include <stdint.h>

// Problem constants (fixed by reference: M=4096, K=4096, N=12288, group=128)
constexpr int Mdim = 4096;
constexpr int Kdim = 4096;
constexpr int Ndim = 12288;

constexpr int NKT = Kdim / 64;          // 64 K-tiles of BK=64
constexpr int GM256 = Mdim / 256;       // 16
constexpr int GN256 = Ndim / 256;       // 48
constexpr int NWG256 = GM256 * GN256;   // 768 (divisible by 8)
constexpr int GRID_M = Mdim / 128;      // 32
constexpr int GRID_N = Ndim / 128;      // 96
constexpr int NWG = GRID_M * GRID_N;    // 3072

typedef float  f32x4   __attribute__((ext_vector_type(4)));
typedef __bf16 bf16x4v __attribute__((ext_vector_type(4)));
typedef __bf16 bf16x8v __attribute__((ext_vector_type(8)));
typedef int    i32x4   __attribute__((ext_vector_type(4)));
typedef unsigned short ushort8 __attribute__((ext_vector_type(8)));

// ---------------------------------------------------------------------------
// global_load_lds: per-lane global src, wave-uniform LDS dest (+lane*16)
// ---------------------------------------------------------------------------
typedef __attribute__((address_space(3))) uint32_t       lds_u32;
typedef __attribute__((address_space(1))) const uint32_t glb_u32;

__device__ __forceinline__ void gload16(const void* g, void* l) {
    __builtin_amdgcn_global_load_lds((glb_u32*)(uintptr_t)g,
                                     (lds_u32*)(uint32_t)(uintptr_t)l, 16, 0, 0);
}

// ===========================================================================
// Swizzle scheme (baked into the prepass global layout):
// within each row, k organized as [kt 0..63][kh 0..1][slot 0..3][elem 0..7];
// logical slot ks stored at position ks ^ ((row>>1)&3).
// ===========================================================================

// Pre-pass 1: A fp32 [M][K] -> bf16 [M][K] with baked swizzle
__launch_bounds__(256)
__global__ void cvtA(const float* __restrict__ A, unsigned short* __restrict__ Aw) {
    int t = blockIdx.x * 256 + threadIdx.x;  // one 16B bf16 chunk (8 elems)
    int r = t >> 9;                          // 512 chunks per row
    int c = t & 511;
    const float* src = A + ((long)r << 12) + (c << 3);
    f32x4 v0 = *(const f32x4*)src;
    f32x4 v1 = *(const f32x4*)(src + 4);
    bf16x8v o;
#pragma unroll
    for (int j = 0; j < 4; ++j) { o[j] = (__bf16)v0[j]; o[4 + j] = (__bf16)v1[j]; }
    int ks = c & 3;
    int cp = (c & ~3) | (ks ^ ((r >> 1) & 3));
    *(bf16x8v*)(Aw + ((long)r << 12) + (cp << 3)) = o;
}

// Pre-pass 2: Bq int32 [K][N] + scales -> bf16 B^T [N][K], baked swizzle
__launch_bounds__(256)
__global__ void deqB(const int* __restrict__ Bq, const float* __restrict__ S,
                     unsigned short* __restrict__ Bw) {
    __shared__ unsigned short lt[64][72];    // 144B row pitch -> 16B-aligned chunks
    int kb = blockIdx.x & 63;                // K/64
    int nb = blockIdx.x >> 6;                // N/64
    int k0 = kb << 6, n0 = nb << 6;
    int tid = threadIdx.x;
    int g = k0 >> 7;                         // scale group
    int nq = (tid & 15) << 2;
    f32x4 sc = *(const f32x4*)(S + (long)g * Ndim + n0 + nq);
#pragma unroll
    for (int p = 0; p < 4; ++p) {
        int kk = (p << 4) + (tid >> 4);
        i32x4 q = *(const i32x4*)(Bq + (long)(k0 + kk) * Ndim + n0 + nq);
#pragma unroll
        for (int j = 0; j < 4; ++j) {
            float v = ((float)q[j] - 8.f) * sc[j];
            lt[nq + j][kk] = __builtin_bit_cast(unsigned short, (__bf16)v);
        }
    }
    __syncthreads();
#pragma unroll
    for (int h = 0; h < 2; ++h) {
        int cidx = tid + (h << 8);           // 512 chunks: n 0..63 x (kh,ks)
        int n = cidx >> 3, sidx = cidx & 7;
        int kh = sidx >> 2, ks = sidx & 3;
        int ksp = ks ^ ((n >> 1) & 3);
        ushort8 v = *(const ushort8*)&lt[n][sidx << 3];
        *(ushort8*)(Bw + (long)(n0 + n) * Kdim + k0 + kh * 32 + ksp * 8) = v;
    }
}

// ===========================================================================
// Main GEMM: 256x256 tile, BK=64, 8 waves (2Mx4N), 4-phase/K-tile schedule
// with ONE-PHASE REGISTER READ-AHEAD (3 A-sets, 2 B-sets rotation),
// counted vmcnt(4) per K-tile, 128 KiB double-buffered LDS.
// ===========================================================================
__device__ __forceinline__ void mfma16(const bf16x8v* a4, const bf16x8v* b4,
                                       f32x4 (*acc)[4]) {
#pragma unroll
    for (int m = 0; m < 4; ++m)
#pragma unroll
        for (int n = 0; n < 4; ++n)
            acc[m][n] = __builtin_amdgcn_mfma_f32_16x16x32_bf16(a4[m], b4[n], acc[m][n], 0, 0, 0);
}

__launch_bounds__(512, 2)
__global__ void gemm256(const unsigned short* __restrict__ Aw,
                        const unsigned short* __restrict__ Bw,
                        float* __restrict__ C) {
    extern __shared__ unsigned char ldsbuf[];

    const int tid  = threadIdx.x;
    const int lane = tid & 63;
    const int w    = tid >> 6;               // wave 0..7
    const int wr   = w >> 2, wc = w & 3;     // 2x4 wave grid; wave tile 128x64
    const int fr   = lane & 15;
    const int ks   = lane >> 4;

    // XCD partition: xcd owns 6 tn panels; tm-major within panel
    const int bid = blockIdx.x;
    const int xcd = bid & 7;
    const int loc = bid >> 3;                // 0..95
    const int pn  = loc >> 4;                // 0..5
    const int tm  = loc & 15;                // 0..15
    const int tn  = xcd * 6 + pn;
    const int brow = tm << 8, bcol = tn << 8;

    const unsigned char* baseA = (const unsigned char*)Aw
        + (size_t)(brow + (tid >> 2)) * 8192 + (size_t)(tid & 3) * 16;
    const unsigned char* baseB = (const unsigned char*)Bw
        + (size_t)(bcol + (tid >> 2)) * 8192 + (size_t)(tid & 3) * 16;

    // fragment read offsets (region-local)
    int offA[8][2], offB[4][2];
#pragma unroll
    for (int am = 0; am < 8; ++am)
#pragma unroll
        for (int kh = 0; kh < 2; ++kh) {
            int rowL = wr * 128 + am * 16 + fr;
            offA[am][kh] = (kh << 14) + rowL * 64 + ((ks ^ ((rowL >> 1) & 3)) << 4);
        }
#pragma unroll
    for (int n = 0; n < 4; ++n)
#pragma unroll
        for (int kh = 0; kh < 2; ++kh) {
            int colL = wc * 64 + n * 16 + fr;
            offB[n][kh] = (kh << 14) + colL * 64 + ((ks ^ ((colL >> 1) & 3)) << 4);
        }

    auto stageA = [&](int tile, int kh) {
        if (tile < NKT) {
            const unsigned char* s = baseA + (size_t)tile * 128 + (kh << 6);
            unsigned char* d = ldsbuf + ((tile & 1) << 16) + (kh << 14) + (w << 10);
            gload16(s, d);
            gload16(s + 1048576, d + 8192);
        }
    };
    auto stageB = [&](int tile, int kh) {
        if (tile < NKT) {
            const unsigned char* s = baseB + (size_t)tile * 128 + (kh << 6);
            unsigned char* d = ldsbuf + ((tile & 1) << 16) + 32768 + (kh << 14) + (w << 10);
            gload16(s, d);
            gload16(s + 1048576, d + 8192);
        }
    };

    f32x4 accT[4][4], accB[4][4];            // top half (mh0), bottom half (mh1)
#pragma unroll
    for (int m = 0; m < 4; ++m)
#pragma unroll
        for (int n = 0; n < 4; ++n) {
            accT[m][n] = (f32x4){0.f, 0.f, 0.f, 0.f};
            accB[m][n] = (f32x4){0.f, 0.f, 0.f, 0.f};
        }

    // prologue: K0 all 4 halves + K1 kh0 halves; vmcnt(4) -> K0 fully landed
    stageA(0, 0); stageB(0, 0); stageA(0, 1); stageB(0, 1);
    stageA(1, 0); stageB(1, 0);
    asm volatile("s_waitcnt vmcnt(4)" ::: "memory");
    __builtin_amdgcn_s_barrier();

    bf16x8v A0[4], A1[4], A2[4], B0[4], B1[4];

    for (int T = 0; T < NKT; ++T) {
        unsigned char* sAc = ldsbuf + ((T & 1) << 16);
        unsigned char* sBc = sAc + 32768;

        // ---- phase 0: MFMA (mh0,kh0). Reads: A0/B0 (this phase) + A1 (next).
#pragma unroll
        for (int m = 0; m < 4; ++m) A0[m] = *(const bf16x8v*)(sAc + offA[m][0]);
#pragma unroll
        for (int n = 0; n < 4; ++n) B0[n] = *(const bf16x8v*)(sBc + offB[n][0]);
#pragma unroll
        for (int m = 0; m < 4; ++m) A1[m] = *(const bf16x8v*)(sAc + offA[4 + m][0]);
        stageA(T + 1, 1);
        __builtin_amdgcn_s_barrier();
        __builtin_amdgcn_s_setprio(1);
        mfma16(A0, B0, accT);                // waits only A0,B0; A1 stays in flight
        __builtin_amdgcn_s_setprio(0);
        __builtin_amdgcn_s_barrier();

        // ---- phase 1: MFMA (mh1,kh0) on A1 (read-ahead). Reads: B1, A2 (kh1).
#pragma unroll
        for (int n = 0; n < 4; ++n) B1[n] = *(const bf16x8v*)(sBc + offB[n][1]);
#pragma unroll
        for (int m = 0; m < 4; ++m) A2[m] = *(const bf16x8v*)(sAc + offA[m][1]);
        stageB(T + 1, 1);
        __builtin_amdgcn_s_barrier();
        __builtin_amdgcn_s_setprio(1);
        mfma16(A1, B0, accB);
        __builtin_amdgcn_s_setprio(0);
        __builtin_amdgcn_s_barrier();

        // ---- phase 2: MFMA (mh0,kh1) on A2/B1 (read-ahead). Reads: A0 <- (mh1,kh1).
#pragma unroll
        for (int m = 0; m < 4; ++m) A0[m] = *(const bf16x8v*)(sAc + offA[4 + m][1]);
        stageA(T + 2, 0);
        __builtin_amdgcn_s_barrier();
        __builtin_amdgcn_s_setprio(1);
        mfma16(A2, B1, accT);
        __builtin_amdgcn_s_setprio(0);
        __builtin_amdgcn_s_barrier();

        // ---- phase 3: MFMA (mh1,kh1) on A0 (read-ahead). No reads.
        stageB(T + 2, 0);
        __builtin_amdgcn_s_barrier();
        __builtin_amdgcn_s_setprio(1);
        mfma16(A0, B1, accB);
        __builtin_amdgcn_s_setprio(0);
        // counted drain: T+2 kh0 loads (4) stay in flight; T+1 fully landed.
        if (T < NKT - 2) asm volatile("s_waitcnt vmcnt(4)" ::: "memory");
        else             asm volatile("s_waitcnt vmcnt(0)" ::: "memory");
        __builtin_amdgcn_s_barrier();
    }

    // epilogue: C/D layout col = lane&15, row = (lane>>4)*4 + r
#pragma unroll
    for (int am = 0; am < 8; ++am) {
        int row = brow + wr * 128 + am * 16 + ks * 4;
#pragma unroll
        for (int n = 0; n < 4; ++n) {
            int col = bcol + wc * 64 + n * 16 + fr;
            f32x4 v = (am < 4) ? accT[am & 3][n] : accB[am & 3][n];
            float* cp = C + (long)row * Ndim + col;
#pragma unroll
            for (int r = 0; r < 4; ++r) cp[(long)r * Ndim] = v[r];
        }
    }
}

// ===========================================================================
// Secondary fallback: 128x128 structure (if hipFuncSetAttribute fails)
// ===========================================================================
__launch_bounds__(256, 3)
__global__ void gemm_bf16(const unsigned short* __restrict__ Aw,
                          const unsigned short* __restrict__ Bw,
                          float* __restrict__ C) {
    __shared__ unsigned char sA[128 * 64 * 2];
    __shared__ unsigned char sB[128 * 64 * 2];

    const int tid  = threadIdx.x;
    const int lane = tid & 63;
    const int w    = tid >> 6;

    const int bid   = blockIdx.x;
    const int x     = bid & 7;
    const int local = bid >> 3;
    const int pn    = local >> 5;
    const int tm    = local & 31;
    const int tn    = x * 12 + pn;
    const int brow  = tm << 7;
    const int bcol  = tn << 7;

    const unsigned char* ga[4];
    const unsigned char* gb[4];
#pragma unroll
    for (int i = 0; i < 4; ++i) {
        int c = (w << 8) + (i << 6) + lane;
        int r = c >> 3, s = c & 7;
        ga[i] = (const unsigned char*)Aw + (long)(brow + r) * 8192 + (s << 4);
        gb[i] = (const unsigned char*)Bw + (long)(bcol + r) * 8192 + (s << 4);
    }

    const int fr = lane & 15;
    const int ks = lane >> 4;
    const int wr = w >> 1, wc = w & 1;
    int ra[4][2], rb[4][2];
#pragma unroll
    for (int m = 0; m < 4; ++m)
#pragma unroll
        for (int kk = 0; kk < 2; ++kk) {
            int r_a = wr * 64 + m * 16 + fr;
            int r_b = wc * 64 + m * 16 + fr;
            ra[m][kk] = (r_a << 7) + (kk << 6) + ((ks ^ ((r_a >> 1) & 3)) << 4);
            rb[m][kk] = (r_b << 7) + (kk << 6) + ((ks ^ ((r_b >> 1) & 3)) << 4);
        }

    f32x4 acc[4][4];
#pragma unroll
    for (int m = 0; m < 4; ++m)
#pragma unroll
        for (int n = 0; n < 4; ++n) acc[m][n] = (f32x4){0.f, 0.f, 0.f, 0.f};

    for (int kt = 0; kt < NKT; ++kt) {
#pragma unroll
        for (int i = 0; i < 4; ++i) {
            gload16(ga[i], sA + (((w << 2) + i) << 10));
            gload16(gb[i], sB + (((w << 2) + i) << 10));
            ga[i] += 128;
            gb[i] += 128;
        }
        __syncthreads();

#pragma unroll
        for (int kk = 0; kk < 2; ++kk) {
            bf16x8v af[4], bf[4];
#pragma unroll
            for (int m = 0; m < 4; ++m) af[m] = *(const bf16x8v*)(sA + ra[m][kk]);
#pragma unroll
            for (int n = 0; n < 4; ++n) bf[n] = *(const bf16x8v*)(sB + rb[n][kk]);
#pragma unroll
            for (int m = 0; m < 4; ++m)
#pragma unroll
                for (int n = 0; n < 4; ++n)
                    acc[m][n] = __builtin_amdgcn_mfma_f32_16x16x32_bf16(af[m], bf[n], acc[m][n], 0, 0, 0);
        }
        __syncthreads();
    }

#pragma unroll
    for (int m = 0; m < 4; ++m) {
        int row = brow + wr * 64 + m * 16 + ks * 4;
#pragma unroll
        for (int n = 0; n < 4; ++n) {
            int col = bcol + wc * 64 + n * 16 + fr;
            f32x4 v = acc[m][n];
            float* cp = C + (long)row * Ndim + col;
#pragma unroll
            for (int r = 0; r < 4; ++r) cp[(long)r * Ndim] = v[r];
        }
    }
}

// ===========================================================================
// Last-resort fallback: fused single-pass (no workspace needed)
// ===========================================================================
__device__ __forceinline__ int swz_f(int row, int kbyte) {
    int s = kbyte >> 4;
    int f = s ^ ((row ^ (row >> 2)) & 7);
    return (row << 7) + (f << 4) + (kbyte & 15);
}

__launch_bounds__(256, 2)
__global__ void machete_fused(const float* __restrict__ A,
                              const int* __restrict__ Bq,
                              const float* __restrict__ S,
                              float* __restrict__ C) {
    __shared__ unsigned char sA[128 * 64 * 2];
    __shared__ unsigned char sB[128 * 64 * 2];

    const int tid = threadIdx.x;
    const int bid = blockIdx.x;
    const int sid = (bid & 7) * (NWG / 8) + (bid >> 3);
    const int tm = sid / GRID_N;
    const int tn = sid % GRID_N;
    const int brow = tm * 128;
    const int bcol = tn * 128;

    const int a_row0 = tid >> 4;
    const int a_kb   = tid & 15;
    const int b_kb = tid >> 4;
    const int b_nb = tid & 15;

    int aw[8];
#pragma unroll
    for (int i = 0; i < 8; ++i) aw[i] = swz_f(a_row0 + 16 * i, a_kb * 8);
    int bw[2][4];
#pragma unroll
    for (int i = 0; i < 2; ++i)
#pragma unroll
        for (int j = 0; j < 4; ++j) bw[i][j] = swz_f(4 * b_nb + 64 * i + j, b_kb * 8);

    const int lane = tid & 63;
    const int w  = tid >> 6;
    const int wr = w >> 1, wc = w & 1;
    const int fr = lane & 15;
    const int ks = lane >> 4;
    int ar[4][2], br[4][2];
#pragma unroll
    for (int m = 0; m < 4; ++m)
#pragma unroll
        for (int kk = 0; kk < 2; ++kk) {
            ar[m][kk] = swz_f(wr * 64 + m * 16 + fr, kk * 64 + ks * 16);
            br[m][kk] = swz_f(wc * 64 + m * 16 + fr, kk * 64 + ks * 16);
        }

    const float* Ap = A + (long)brow * Kdim;
    const int*   Bp = Bq + bcol;

    f32x4 aregs[8];
    i32x4 bregs[2][4];
    f32x4 sregs[2];

#pragma unroll
    for (int i = 0; i < 8; ++i)
        aregs[i] = *(const f32x4*)(Ap + (long)(a_row0 + 16 * i) * Kdim + a_kb * 4);
#pragma unroll
    for (int i = 0; i < 2; ++i) {
#pragma unroll
        for (int r = 0; r < 4; ++r)
            bregs[i][r] = *(const i32x4*)(Bp + (long)(b_kb * 4 + r) * Ndim + 4 * b_nb + 64 * i);
        sregs[i] = *(const f32x4*)(S + bcol + 4 * b_nb + 64 * i);
    }

    f32x4 acc[4][4];
#pragma unroll
    for (int m = 0; m < 4; ++m)
#pragma unroll
        for (int n = 0; n < 4; ++n) acc[m][n] = (f32x4){0.f, 0.f, 0.f, 0.f};

    for (int kt = 0; kt < NKT; ++kt) {
#pragma unroll
        for (int i = 0; i < 8; ++i) {
            f32x4 v = aregs[i];
            bf16x4v p;
            p[0] = (__bf16)v[0]; p[1] = (__bf16)v[1];
            p[2] = (__bf16)v[2]; p[3] = (__bf16)v[3];
            *(bf16x4v*)(sA + aw[i]) = p;
        }
#pragma unroll
        for (int i = 0; i < 2; ++i) {
            f32x4 sc = sregs[i];
#pragma unroll
            for (int j = 0; j < 4; ++j) {
                float scj = sc[j];
                float nm8 = -8.f * scj;
                bf16x4v p;
#pragma unroll
                for (int r = 0; r < 4; ++r) {
                    float v = (float)bregs[i][r][j] * scj + nm8;
                    p[r] = (__bf16)v;
                }
                *(bf16x4v*)(sB + bw[i][j]) = p;
            }
        }
        __syncthreads();

        if (kt + 1 < NKT) {
            const float* Ap2 = Ap + (kt + 1) * 64;
            const int*   Bp2 = Bq + bcol + (long)((kt + 1) * 64) * Ndim;
            const float* Sp2 = S + (long)((kt + 1) >> 1) * Ndim + bcol;
#pragma unroll
            for (int i = 0; i < 8; ++i)
                aregs[i] = *(const f32x4*)(Ap2 + (long)(a_row0 + 16 * i) * Kdim + a_kb * 4);
#pragma unroll
            for (int i = 0; i < 2; ++i) {
#pragma unroll
                for (int r = 0; r < 4; ++r)
                    bregs[i][r] = *(const i32x4*)(Bp2 + (long)(b_kb * 4 + r) * Ndim + 4 * b_nb + 64 * i);
                sregs[i] = *(const f32x4*)(Sp2 + 4 * b_nb + 64 * i);
            }
        }

#pragma unroll
        for (int kk = 0; kk < 2; ++kk) {
            bf16x8v af[4], bfv[4];
#pragma unroll
            for (int m = 0; m < 4; ++m) af[m] = *(const bf16x8v*)(sA + ar[m][kk]);
#pragma unroll
            for (int n = 0; n < 4; ++n) bfv[n] = *(const bf16x8v*)(sB + br[n][kk]);
#pragma unroll
            for (int m = 0; m < 4; ++m)
#pragma unroll
                for (int n = 0; n < 4; ++n)
                    acc[m][n] = __builtin_amdgcn_mfma_f32_16x16x32_bf16(af[m], bfv[n], acc[m][n], 0, 0, 0);
        }
        __syncthreads();
    }

#pragma unroll
    for (int m = 0; m < 4; ++m) {
        int row = brow + wr * 64 + m * 16 + ks * 4;
#pragma unroll
        for (int n = 0; n < 4; ++n) {
            int col = bcol + wc * 64 + n * 16 + fr;
            f32x4 v = acc[m][n];
            float* cp = C + (long)row * Ndim + col;
#pragma unroll
            for (int r = 0; r < 4; ++r) cp[(long)r * Ndim] = v[r];
        }
    }
}

extern "C" void kernel_launch(void* const* d_in, const int* in_sizes, int n_in,
                              void* d_out, int out_size, void* d_ws, size_t ws_size,
                              hipStream_t stream) {
    const float* A  = (const float*)d_in[0];
    const int*   Bq = (const int*)d_in[1];
    const float* S  = (const float*)d_in[2];
    float* C = (float*)d_out;

    const size_t a_elems = (size_t)Mdim * Kdim;
    const size_t b_elems = (size_t)Ndim * Kdim;
    const size_t need = (a_elems + b_elems) * sizeof(unsigned short);

    if (ws_size >= need) {
        unsigned short* Aw = (unsigned short*)d_ws;
        unsigned short* Bw = Aw + a_elems;
        hipLaunchKernelGGL(cvtA, dim3((Mdim * Kdim / 8) / 256), dim3(256), 0, stream, A, Aw);
        hipLaunchKernelGGL(deqB, dim3((Kdim / 64) * (Ndim / 64)), dim3(256), 0, stream, Bq, S, Bw);
        hipError_t e = hipFuncSetAttribute(
            reinterpret_cast<const void*>(gemm256),
            hipFuncAttributeMaxDynamicSharedMemorySize, 131072);
        if (e == hipSuccess) {
            hipLaunchKernelGGL(gemm256, dim3(NWG256), dim3(512), 131072, stream, Aw, Bw, C);
        } else {
            hipLaunchKernelGGL(gemm_bf16, dim3(NWG), dim3(256), 0, stream, Aw, Bw, C);
        }
    } else {
        hipLaunchKernelGGL(machete_fused, dim3(NWG), dim3(256), 0, stream, A, Bq, S, C);
    }
}